// Round 6
// baseline (20850.130 us; speedup 1.0000x reference)
//
#include <hip/hip_runtime.h>
#include <math.h>

#define N_NODES 100000
#define N_EDGES 1600000
#define IN_C 128
#define HID_C 128
#define OUT_C 64
#define NLAYERS 4
#define KSTEPS 10
#define ALPHA 0.1f
#define LN_EPS 1e-5f

#define SCAN_N (N_NODES + 1)
#define SCAN_BLOCKS ((SCAN_N + 1023) / 1024)   // 98
#define NGROUPS 3125                            // 100000 / 32 nodes per group
#define SLAB_STRIDE ((size_t)N_NODES * 8)       // dwords per 16-ch slab
#define EDGE_SLACK 256

__device__ __forceinline__ float gelu_exact(float x) {
    return 0.5f * x * (1.0f + erff(x * 0.70710678118654752f));
}
__device__ __forceinline__ unsigned pack_bf16_rne(float a, float b) {
    unsigned ua = __float_as_uint(a);
    unsigned ub = __float_as_uint(b);
    ua = (ua + 0x7fffu + ((ua >> 16) & 1u)) >> 16;
    ub = (ub + 0x7fffu + ((ub >> 16) & 1u)) >> 16;
    return (ub << 16) | ua;
}
__device__ __forceinline__ unsigned short bf16_of(float a) {
    unsigned ua = __float_as_uint(a);
    return (unsigned short)((ua + 0x7fffu + ((ua >> 16) & 1u)) >> 16);
}
__device__ __forceinline__ float bf_lo(unsigned d) { return __uint_as_float(d << 16); }
__device__ __forceinline__ float bf_hi(unsigned d) { return __uint_as_float(d & 0xffff0000u); }

// ---------------------------------------------------------------------------
// CSR build
__global__ void count_k(const int* __restrict__ dst, int* __restrict__ counts) {
    int e = blockIdx.x * blockDim.x + threadIdx.x;
    if (e < N_EDGES) atomicAdd(&counts[dst[e]], 1);
}

__global__ __launch_bounds__(1024) void scan1_k(const int* __restrict__ counts,
                                                int* __restrict__ bsum) {
    __shared__ int s[1024];
    int i = blockIdx.x * 1024 + threadIdx.x;
    int c = (i < N_NODES) ? counts[i] : 0;
    s[threadIdx.x] = c;
    __syncthreads();
    for (int off = 512; off; off >>= 1) {
        if (threadIdx.x < off) s[threadIdx.x] += s[threadIdx.x + off];
        __syncthreads();
    }
    if (threadIdx.x == 0) bsum[blockIdx.x] = s[0];
}

__global__ void scan2_k(int* __restrict__ bsum) {
    __shared__ int s[128];
    int t = threadIdx.x;
    s[t] = (t < SCAN_BLOCKS) ? bsum[t] : 0;
    __syncthreads();
    for (int off = 1; off < 128; off <<= 1) {
        int v = (t >= off) ? s[t - off] : 0;
        __syncthreads();
        s[t] += v;
        __syncthreads();
    }
    if (t < SCAN_BLOCKS) bsum[t] = (t == 0) ? 0 : s[t - 1];
}

__global__ __launch_bounds__(1024) void scan3_k(const int* __restrict__ counts,
                                                const int* __restrict__ bsum,
                                                int* __restrict__ row_off,
                                                int* __restrict__ fill_pos) {
    __shared__ int s[1024];
    int i = blockIdx.x * 1024 + threadIdx.x;
    int c = (i < N_NODES) ? counts[i] : 0;
    s[threadIdx.x] = c;
    __syncthreads();
    for (int off = 1; off < 1024; off <<= 1) {
        int v = (threadIdx.x >= off) ? s[threadIdx.x - off] : 0;
        __syncthreads();
        s[threadIdx.x] += v;
        __syncthreads();
    }
    if (i <= N_NODES) {
        int excl = s[threadIdx.x] - c + bsum[blockIdx.x];
        row_off[i] = excl;
        fill_pos[i] = excl;
    }
}

// Degree-bucket counting sort: ord[] = node ids grouped by min(deg,63).
__global__ __launch_bounds__(1024) void hist_k(const int* __restrict__ counts,
                                               int* __restrict__ hist) {
    __shared__ int h[64];
    if (threadIdx.x < 64) h[threadIdx.x] = 0;
    __syncthreads();
    int i = blockIdx.x * 1024 + threadIdx.x;
    if (i < N_NODES) atomicAdd(&h[min(counts[i], 63)], 1);
    __syncthreads();
    if (threadIdx.x < 64 && h[threadIdx.x]) atomicAdd(&hist[threadIdx.x], h[threadIdx.x]);
}

__global__ void hscan_k(const int* __restrict__ hist, int* __restrict__ hpos) {
    int t = threadIdx.x;                    // block = 64
    int c = hist[t];
    int v = c;
    for (int off = 1; off < 64; off <<= 1) {
        int u = __shfl_up(v, off);
        if (t >= off) v += u;
    }
    hpos[t] = v - c;                        // exclusive
}

__global__ void ordscat_k(const int* __restrict__ counts, int* __restrict__ hpos,
                          int* __restrict__ ord) {
    int i = blockIdx.x * 256 + threadIdx.x;
    if (i >= N_NODES) return;
    int b = min(counts[i], 63);
    int pos = atomicAdd(&hpos[b], 1);
    ord[pos] = i;
}

// Bucket edges by dst into split arrays: esrc = src*8 (slab dword offset),
// ew = (1-alpha)*w in bf16.
__global__ void bucket_k(const int* __restrict__ src, const int* __restrict__ dst,
                         const float* __restrict__ w, int* __restrict__ fill_pos,
                         unsigned* __restrict__ esrc, unsigned short* __restrict__ ew) {
    int e = blockIdx.x * blockDim.x + threadIdx.x;
    if (e >= N_EDGES) return;
    int d = dst[e];
    int pos = atomicAdd(&fill_pos[d], 1);
    esrc[pos] = (unsigned)(src[e] << 3);
    ew[pos] = bf16_of((1.0f - ALPHA) * w[e]);
}

// ---------------------------------------------------------------------------
// Encoder: H(bf16, slab-major) = gelu(LN(x @ Wenc^T)).
// Lane l holds dword l of the row (= ch 2l,2l+1) -> slab l>>3, within-slab l&7.
__global__ __launch_bounds__(1024) void encoder_k(
        const float* __restrict__ x, const float* __restrict__ Wenc,
        const float* __restrict__ gamma, const float* __restrict__ beta,
        unsigned* __restrict__ H) {
    __shared__ float WT[IN_C * 130];
    __shared__ float XS[16][512];
    for (int i = threadIdx.x; i < IN_C * HID_C; i += 1024) {
        int c = i >> 7, k = i & 127;
        WT[k * 130 + c] = Wenc[i];
    }
    __syncthreads();
    int lane = threadIdx.x & 63;
    int wid  = threadIdx.x >> 6;
    const float2* WT2 = (const float2*)WT;     // index k*65 + lane
    float2 gb = ((const float2*)gamma)[lane];
    float2 bb = ((const float2*)beta)[lane];
    int wstride = gridDim.x * 16;
    float* xs = XS[wid];
    size_t slab_off = (size_t)(lane >> 3) * SLAB_STRIDE + (lane & 7);
    for (int grp = blockIdx.x * 16 + wid; grp * 4 < N_NODES; grp += wstride) {
        int r0 = grp * 4;
        const float4* xr = (const float4*)(x + (size_t)r0 * IN_C);
        ((float4*)xs)[lane]      = xr[lane];
        ((float4*)xs)[64 + lane] = xr[64 + lane];
        __builtin_amdgcn_wave_barrier();
        float a0x = 0, a0y = 0, a1x = 0, a1y = 0;
        float a2x = 0, a2y = 0, a3x = 0, a3y = 0;
        const float4* xs4 = (const float4*)xs;
#pragma unroll 4
        for (int k4 = 0; k4 < 32; ++k4) {
            float4 xv0 = xs4[k4];
            float4 xv1 = xs4[32 + k4];
            float4 xv2 = xs4[64 + k4];
            float4 xv3 = xs4[96 + k4];
            int k = k4 * 4;
            float2 w0 = WT2[(k + 0) * 65 + lane];
            float2 w1 = WT2[(k + 1) * 65 + lane];
            float2 w2 = WT2[(k + 2) * 65 + lane];
            float2 w3 = WT2[(k + 3) * 65 + lane];
#define ENC_ROW(ax, ay, xv)                                      \
            ax = fmaf(xv.x, w0.x, ax); ay = fmaf(xv.x, w0.y, ay); \
            ax = fmaf(xv.y, w1.x, ax); ay = fmaf(xv.y, w1.y, ay); \
            ax = fmaf(xv.z, w2.x, ax); ay = fmaf(xv.z, w2.y, ay); \
            ax = fmaf(xv.w, w3.x, ax); ay = fmaf(xv.w, w3.y, ay);
            ENC_ROW(a0x, a0y, xv0)
            ENC_ROW(a1x, a1y, xv1)
            ENC_ROW(a2x, a2y, xv2)
            ENC_ROW(a3x, a3y, xv3)
#undef ENC_ROW
        }
        __builtin_amdgcn_wave_barrier();
#define ENC_EPI(ax, ay, row)                                               \
        {                                                                   \
            float sum = ax + ay;                                            \
            for (int off = 32; off; off >>= 1) sum += __shfl_xor(sum, off); \
            float mu = sum * (1.0f / 128.0f);                               \
            float d0 = ax - mu, d1 = ay - mu;                               \
            float vs = d0 * d0 + d1 * d1;                                   \
            for (int off = 32; off; off >>= 1) vs += __shfl_xor(vs, off);   \
            float inv = rsqrtf(vs * (1.0f / 128.0f) + LN_EPS);              \
            float o0 = gelu_exact(gb.x * d0 * inv + bb.x);                  \
            float o1 = gelu_exact(gb.y * d1 * inv + bb.y);                  \
            H[slab_off + (size_t)(row) * 8] = pack_bf16_rne(o0, o1);        \
        }
        ENC_EPI(a0x, a0y, r0)
        ENC_EPI(a1x, a1y, r0 + 1)
        ENC_EPI(a2x, a2y, r0 + 2)
        ENC_EPI(a3x, a3y, r0 + 3)
#undef ENC_EPI
    }
}

// ---------------------------------------------------------------------------
// One APPNP step, channel-slab partitioned. Block -> slab s (blockIdx&7 with
// per-slab work-stealing queues: correctness never depends on XCD mapping).
// Wave: 8 dst nodes (degree-sorted via ord) x 8 dwords; lanes j=lane>>3 (node),
// d=lane&7 (dword). One gather instr serves 8 edges x 32 B. 4 edges/iter ILP.
__global__ __launch_bounds__(256) void prop_k(
        const unsigned* __restrict__ zin, const unsigned* __restrict__ x0,
        const int* __restrict__ row_off,
        const unsigned* __restrict__ esrc, const unsigned short* __restrict__ ew,
        const int* __restrict__ ord, int* __restrict__ q,
        unsigned* __restrict__ zout) {
    __shared__ int sh_g;
    int lane = threadIdx.x & 63;
    int wv = threadIdx.x >> 6;
    int j = lane >> 3, d = lane & 7;
    int myslab = blockIdx.x & 7;
    for (int t = 0; t < 8; ++t) {
        int s = (myslab + t) & 7;
        const unsigned* zs = zin + (size_t)s * SLAB_STRIDE;
        const unsigned* xsl = x0 + (size_t)s * SLAB_STRIDE;
        unsigned* zo = zout + (size_t)s * SLAB_STRIDE;
        while (true) {
            __syncthreads();
            if (threadIdx.x == 0) sh_g = atomicAdd(&q[s], 1);
            __syncthreads();
            int g = sh_g;
            if (g >= NGROUPS) break;
            int node = ord[g * 32 + wv * 8 + j];
            int e0 = row_off[node];
            int deg = row_off[node + 1] - e0;
            int m = deg;
            m = max(m, __shfl_xor(m, 8));
            m = max(m, __shfl_xor(m, 16));
            m = max(m, __shfl_xor(m, 32));      // group (8-node) max degree
            float ax = 0.f, ay = 0.f;
            for (int it = 0; it < m; it += 4) {
                int i0 = e0 + it;
                unsigned sA = esrc[i0];
                unsigned sB = esrc[i0 + 1];
                unsigned sC = esrc[i0 + 2];
                unsigned sD = esrc[i0 + 3];
                unsigned wa = ew[i0];
                unsigned wb = ew[i0 + 1];
                unsigned wc = ew[i0 + 2];
                unsigned wd = ew[i0 + 3];
                unsigned vA = zs[sA + d];
                unsigned vB = zs[sB + d];
                unsigned vC = zs[sC + d];
                unsigned vD = zs[sD + d];
                float wA = (it     < deg) ? __uint_as_float(wa << 16) : 0.f;
                float wB = (it + 1 < deg) ? __uint_as_float(wb << 16) : 0.f;
                float wC = (it + 2 < deg) ? __uint_as_float(wc << 16) : 0.f;
                float wD = (it + 3 < deg) ? __uint_as_float(wd << 16) : 0.f;
                ax = fmaf(wA, bf_lo(vA), ax); ay = fmaf(wA, bf_hi(vA), ay);
                ax = fmaf(wB, bf_lo(vB), ax); ay = fmaf(wB, bf_hi(vB), ay);
                ax = fmaf(wC, bf_lo(vC), ax); ay = fmaf(wC, bf_hi(vC), ay);
                ax = fmaf(wD, bf_lo(vD), ax); ay = fmaf(wD, bf_hi(vD), ay);
            }
            unsigned xd = xsl[(size_t)node * 8 + d];
            float zx = fmaf(ALPHA, bf_lo(xd), ax);
            float zy = fmaf(ALPHA, bf_hi(xd), ay);
            zo[(size_t)node * 8 + d] = pack_bf16_rne(zx, zy);
        }
    }
}

// ---------------------------------------------------------------------------
// Layer boundary: H = LN(gelu(z)), slab-major in/out. Wave per node;
// lane l <-> dword l (slab l>>3, pos l&7) = channels (2l, 2l+1).
__global__ __launch_bounds__(256) void gelu_ln_k(
        const unsigned* __restrict__ z, const float* __restrict__ gamma,
        const float* __restrict__ beta, unsigned* __restrict__ H) {
    int node = (blockIdx.x * 256 + threadIdx.x) >> 6;
    if (node >= N_NODES) return;
    int lane = threadIdx.x & 63;
    size_t addr = (size_t)(lane >> 3) * SLAB_STRIDE + (size_t)node * 8 + (lane & 7);
    unsigned zd = z[addr];
    float h0 = gelu_exact(bf_lo(zd));
    float h1 = gelu_exact(bf_hi(zd));
    float sum = h0 + h1;
    for (int off = 32; off; off >>= 1) sum += __shfl_xor(sum, off);
    float mu = sum * (1.0f / 128.0f);
    float d0 = h0 - mu, d1 = h1 - mu;
    float vs = d0 * d0 + d1 * d1;
    for (int off = 32; off; off >>= 1) vs += __shfl_xor(vs, off);
    float inv = rsqrtf(vs * (1.0f / 128.0f) + LN_EPS);
    float2 gb = ((const float2*)gamma)[lane];
    float2 bb = ((const float2*)beta)[lane];
    H[addr] = pack_bf16_rne(gb.x * d0 * inv + bb.x, gb.y * d1 * inv + bb.y);
}

// ---------------------------------------------------------------------------
// Decoder: out(fp32) = H(bf16 slab-major) @ Wdec^T -> [N, 64].
__global__ __launch_bounds__(1024) void decoder_k(
        const unsigned* __restrict__ H, const float* __restrict__ Wdec,
        float* __restrict__ out) {
    __shared__ float WT[HID_C * 65];
    __shared__ unsigned XS[16][256];
    for (int i = threadIdx.x; i < OUT_C * HID_C; i += 1024) {
        int o = i >> 7, k = i & 127;
        WT[k * 65 + o] = Wdec[i];
    }
    __syncthreads();
    int lane = threadIdx.x & 63;
    int wid  = threadIdx.x >> 6;
    int wstride = gridDim.x * 16;
    unsigned* xs = XS[wid];
    size_t slab_off = (size_t)(lane >> 3) * SLAB_STRIDE + (lane & 7);
    for (int grp = blockIdx.x * 16 + wid; grp * 4 < N_NODES; grp += wstride) {
        int r0 = grp * 4;
        xs[lane]       = H[slab_off + (size_t)r0 * 8];
        xs[64 + lane]  = H[slab_off + (size_t)(r0 + 1) * 8];
        xs[128 + lane] = H[slab_off + (size_t)(r0 + 2) * 8];
        xs[192 + lane] = H[slab_off + (size_t)(r0 + 3) * 8];
        __builtin_amdgcn_wave_barrier();
        float a0 = 0, a1 = 0, a2 = 0, a3 = 0;
#pragma unroll 4
        for (int k2 = 0; k2 < 64; ++k2) {
            float w0 = WT[(2 * k2) * 65 + lane];
            float w1 = WT[(2 * k2 + 1) * 65 + lane];
            unsigned u0 = xs[k2];
            unsigned u1 = xs[64 + k2];
            unsigned u2 = xs[128 + k2];
            unsigned u3 = xs[192 + k2];
            a0 = fmaf(bf_lo(u0), w0, a0); a0 = fmaf(bf_hi(u0), w1, a0);
            a1 = fmaf(bf_lo(u1), w0, a1); a1 = fmaf(bf_hi(u1), w1, a1);
            a2 = fmaf(bf_lo(u2), w0, a2); a2 = fmaf(bf_hi(u2), w1, a2);
            a3 = fmaf(bf_lo(u3), w0, a3); a3 = fmaf(bf_hi(u3), w1, a3);
        }
        __builtin_amdgcn_wave_barrier();
        out[(size_t)r0 * OUT_C + lane]       = a0;
        out[(size_t)(r0 + 1) * OUT_C + lane] = a1;
        out[(size_t)(r0 + 2) * OUT_C + lane] = a2;
        out[(size_t)(r0 + 3) * OUT_C + lane] = a3;
    }
}

// ---------------------------------------------------------------------------
extern "C" void kernel_launch(void* const* d_in, const int* in_sizes, int n_in,
                              void* d_out, int out_size, void* d_ws, size_t ws_size,
                              hipStream_t stream) {
    const float* x     = (const float*)d_in[0];
    const int*   ei    = (const int*)d_in[1];
    const float* ew_in = (const float*)d_in[2];
    const float* Wenc  = (const float*)d_in[3];
    const float* Wdec  = (const float*)d_in[4];
    const float* gamma = (const float*)d_in[5];
    const float* beta  = (const float*)d_in[6];
    float* out = (float*)d_out;

    const int* src = ei;
    const int* dst = ei + N_EDGES;

    char* p = (char*)d_ws;
    auto carve = [&](size_t bytes) -> void* {
        void* r = (void*)p;
        p += (bytes + 255) & ~(size_t)255;
        return r;
    };
    int*  counts  = (int*)carve(SCAN_N * sizeof(int));
    int*  fillpos = (int*)carve(SCAN_N * sizeof(int));
    int*  row_off = (int*)carve(SCAN_N * sizeof(int));
    int*  bsum    = (int*)carve(SCAN_BLOCKS * sizeof(int));
    int*  hist    = (int*)carve(64 * sizeof(int));
    int*  hpos    = (int*)carve(64 * sizeof(int));
    int*  ord     = (int*)carve(N_NODES * sizeof(int));
    int*  q       = (int*)carve(NLAYERS * KSTEPS * 8 * sizeof(int));
    unsigned*       esrc = (unsigned*)carve((N_EDGES + EDGE_SLACK) * sizeof(unsigned));
    unsigned short* ewb  = (unsigned short*)carve((N_EDGES + EDGE_SLACK) * sizeof(unsigned short));
    unsigned* H  = (unsigned*)carve(8 * SLAB_STRIDE * sizeof(unsigned));
    unsigned* ZA = (unsigned*)carve(8 * SLAB_STRIDE * sizeof(unsigned));
    unsigned* ZB = (unsigned*)carve(8 * SLAB_STRIDE * sizeof(unsigned));

    // Per-launch init
    hipMemsetAsync(counts, 0, SCAN_N * sizeof(int), stream);
    hipMemsetAsync(hist, 0, 64 * sizeof(int), stream);
    hipMemsetAsync(q, 0, NLAYERS * KSTEPS * 8 * sizeof(int), stream);
    hipMemsetAsync(esrc + N_EDGES, 0, EDGE_SLACK * sizeof(unsigned), stream);
    hipMemsetAsync(ewb + N_EDGES, 0, EDGE_SLACK * sizeof(unsigned short), stream);

    // CSR + degree sort
    count_k<<<(N_EDGES + 255) / 256, 256, 0, stream>>>(dst, counts);
    scan1_k<<<SCAN_BLOCKS, 1024, 0, stream>>>(counts, bsum);
    scan2_k<<<1, 128, 0, stream>>>(bsum);
    scan3_k<<<SCAN_BLOCKS, 1024, 0, stream>>>(counts, bsum, row_off, fillpos);
    hist_k<<<SCAN_BLOCKS, 1024, 0, stream>>>(counts, hist);
    hscan_k<<<1, 64, 0, stream>>>(hist, hpos);
    ordscat_k<<<(N_NODES + 255) / 256, 256, 0, stream>>>(counts, hpos, ord);
    bucket_k<<<(N_EDGES + 255) / 256, 256, 0, stream>>>(src, dst, ew_in, fillpos,
                                                        esrc, ewb);

    // Encoder
    encoder_k<<<512, 1024, 0, stream>>>(x, Wenc, gamma, beta, H);

    unsigned* bufs[2] = {ZA, ZB};
    for (int l = 0; l < NLAYERS; ++l) {
        const unsigned* zin = H;                  // x0 = H (layer input)
        for (int k = 0; k < KSTEPS; ++k) {
            unsigned* zout = bufs[k & 1];
            prop_k<<<2048, 256, 0, stream>>>(zin, H, row_off, esrc, ewb, ord,
                                             q + 8 * (l * KSTEPS + k), zout);
            zin = zout;
        }
        gelu_ln_k<<<(N_NODES * 64 + 255) / 256, 256, 0, stream>>>(zin, gamma, beta, H);
    }

    decoder_k<<<512, 1024, 0, stream>>>(H, Wdec, out);
}

// Round 7
// 2855.965 us; speedup vs baseline: 7.3006x; 7.3006x over previous
//
#include <hip/hip_runtime.h>
#include <math.h>

#define N_NODES 100000
#define N_EDGES 1600000
#define IN_C 128
#define HID_C 128
#define OUT_C 64
#define NLAYERS 4
#define KSTEPS 10
#define ALPHA 0.1f
#define LN_EPS 1e-5f

#define SCAN_N (N_NODES + 1)
#define SCAN_BLOCKS ((SCAN_N + 1023) / 1024)     // 98
#define EP_CAP 2400000                            // 1.6M edges + <=7 pad/node

__device__ __forceinline__ float gelu_exact(float x) {
    return 0.5f * x * (1.0f + erff(x * 0.70710678118654752f));
}
__device__ __forceinline__ unsigned pack_bf16_rne(float a, float b) {
    unsigned ua = __float_as_uint(a);
    unsigned ub = __float_as_uint(b);
    ua = (ua + 0x7fffu + ((ua >> 16) & 1u)) >> 16;
    ub = (ub + 0x7fffu + ((ub >> 16) & 1u)) >> 16;
    return (ub << 16) | ua;
}
__device__ __forceinline__ float bf_lo(unsigned d) { return __uint_as_float(d << 16); }
__device__ __forceinline__ float bf_hi(unsigned d) { return __uint_as_float(d & 0xffff0000u); }

// ---------------------------------------------------------------------------
// CSR build: count in-degree per dst
__global__ void count_k(const int* __restrict__ dst, int* __restrict__ counts) {
    int e = blockIdx.x * blockDim.x + threadIdx.x;
    if (e < N_EDGES) atomicAdd(&counts[dst[e]], 1);
}

// scan1: per-block sums of padded (x8) counts
__global__ __launch_bounds__(1024) void scan1_k(const int* __restrict__ counts,
                                                int* __restrict__ bsum) {
    __shared__ int s[1024];
    int i = blockIdx.x * 1024 + threadIdx.x;
    int c = 0;
    if (i < N_NODES) c = (counts[i] + 7) & ~7;
    s[threadIdx.x] = c;
    __syncthreads();
    for (int off = 512; off; off >>= 1) {
        if (threadIdx.x < off) s[threadIdx.x] += s[threadIdx.x + off];
        __syncthreads();
    }
    if (threadIdx.x == 0) bsum[blockIdx.x] = s[0];
}

// scan2: exclusive scan of the 98 block sums
__global__ void scan2_k(int* __restrict__ bsum) {
    __shared__ int s[128];
    int t = threadIdx.x;
    s[t] = (t < SCAN_BLOCKS) ? bsum[t] : 0;
    __syncthreads();
    for (int off = 1; off < 128; off <<= 1) {
        int v = (t >= off) ? s[t - off] : 0;
        __syncthreads();
        s[t] += v;
        __syncthreads();
    }
    if (t < SCAN_BLOCKS) bsum[t] = (t == 0) ? 0 : s[t - 1];
}

// scan3: per-block exclusive scan + block offset -> row_off / fill_pos
__global__ __launch_bounds__(1024) void scan3_k(const int* __restrict__ counts,
                                                const int* __restrict__ bsum,
                                                int* __restrict__ row_off,
                                                int* __restrict__ fill_pos) {
    __shared__ int s[1024];
    int i = blockIdx.x * 1024 + threadIdx.x;
    int c = 0;
    if (i < N_NODES) c = (counts[i] + 7) & ~7;
    s[threadIdx.x] = c;
    __syncthreads();
    for (int off = 1; off < 1024; off <<= 1) {
        int v = (threadIdx.x >= off) ? s[threadIdx.x - off] : 0;
        __syncthreads();
        s[threadIdx.x] += v;
        __syncthreads();
    }
    if (i <= N_NODES) {
        int excl = s[threadIdx.x] - c + bsum[blockIdx.x];
        row_off[i] = excl;
        fill_pos[i] = excl;
    }
}

// Bucket edges by dst; pack (src*64 [dword row offset], (1-alpha)*w fp32).
// Pad slots stay (0,0.0f) from the ep memset -> gather row 0 * 0 -> no-op.
__global__ void bucket_k(const int* __restrict__ src, const int* __restrict__ dst,
                         const float* __restrict__ w,
                         int* __restrict__ fill_pos, int2* __restrict__ ep) {
    int e = blockIdx.x * blockDim.x + threadIdx.x;
    if (e >= N_EDGES) return;
    int d = dst[e];
    int pos = atomicAdd(&fill_pos[d], 1);
    float ws = (1.0f - ALPHA) * w[e];
    ep[pos] = make_int2(src[e] << 6, __float_as_int(ws));
}

// ---------------------------------------------------------------------------
// Encoder: H(bf16) = gelu(LN(x @ Wenc^T)).  (R5 structure, proven)
__global__ __launch_bounds__(1024) void encoder_k(
        const float* __restrict__ x, const float* __restrict__ Wenc,
        const float* __restrict__ gamma, const float* __restrict__ beta,
        unsigned* __restrict__ H) {
    __shared__ float WT[IN_C * 130];           // WT[k*130 + c]
    __shared__ float XS[16][512];              // per-wave 4-row x tile
    for (int i = threadIdx.x; i < IN_C * HID_C; i += 1024) {
        int c = i >> 7, k = i & 127;
        WT[k * 130 + c] = Wenc[i];
    }
    __syncthreads();
    int lane = threadIdx.x & 63;
    int wid  = threadIdx.x >> 6;
    const float2* WT2 = (const float2*)WT;     // index k*65 + lane
    float2 gb = ((const float2*)gamma)[lane];
    float2 bb = ((const float2*)beta)[lane];
    int wstride = gridDim.x * 16;
    float* xs = XS[wid];
    for (int grp = blockIdx.x * 16 + wid; grp * 4 < N_NODES; grp += wstride) {
        int r0 = grp * 4;
        const float4* xr = (const float4*)(x + (size_t)r0 * IN_C);
        ((float4*)xs)[lane]      = xr[lane];
        ((float4*)xs)[64 + lane] = xr[64 + lane];
        __builtin_amdgcn_wave_barrier();
        float a0x = 0, a0y = 0, a1x = 0, a1y = 0;
        float a2x = 0, a2y = 0, a3x = 0, a3y = 0;
        const float4* xs4 = (const float4*)xs;
#pragma unroll 4
        for (int k4 = 0; k4 < 32; ++k4) {
            float4 xv0 = xs4[k4];
            float4 xv1 = xs4[32 + k4];
            float4 xv2 = xs4[64 + k4];
            float4 xv3 = xs4[96 + k4];
            int k = k4 * 4;
            float2 w0 = WT2[(k + 0) * 65 + lane];
            float2 w1 = WT2[(k + 1) * 65 + lane];
            float2 w2 = WT2[(k + 2) * 65 + lane];
            float2 w3 = WT2[(k + 3) * 65 + lane];
#define ENC_ROW(ax, ay, xv)                                      \
            ax = fmaf(xv.x, w0.x, ax); ay = fmaf(xv.x, w0.y, ay); \
            ax = fmaf(xv.y, w1.x, ax); ay = fmaf(xv.y, w1.y, ay); \
            ax = fmaf(xv.z, w2.x, ax); ay = fmaf(xv.z, w2.y, ay); \
            ax = fmaf(xv.w, w3.x, ax); ay = fmaf(xv.w, w3.y, ay);
            ENC_ROW(a0x, a0y, xv0)
            ENC_ROW(a1x, a1y, xv1)
            ENC_ROW(a2x, a2y, xv2)
            ENC_ROW(a3x, a3y, xv3)
#undef ENC_ROW
        }
        __builtin_amdgcn_wave_barrier();
#define ENC_EPI(ax, ay, row)                                               \
        {                                                                   \
            float sum = ax + ay;                                            \
            for (int off = 32; off; off >>= 1) sum += __shfl_xor(sum, off); \
            float mu = sum * (1.0f / 128.0f);                               \
            float d0 = ax - mu, d1 = ay - mu;                               \
            float vs = d0 * d0 + d1 * d1;                                   \
            for (int off = 32; off; off >>= 1) vs += __shfl_xor(vs, off);   \
            float inv = rsqrtf(vs * (1.0f / 128.0f) + LN_EPS);              \
            float o0 = gelu_exact(gb.x * d0 * inv + bb.x);                  \
            float o1 = gelu_exact(gb.y * d1 * inv + bb.y);                  \
            H[(size_t)(row)*64 + lane] = pack_bf16_rne(o0, o1);             \
        }
        ENC_EPI(a0x, a0y, r0)
        ENC_EPI(a1x, a1y, r0 + 1)
        ENC_EPI(a2x, a2y, r0 + 2)
        ENC_EPI(a3x, a3y, r0 + 3)
#undef ENC_EPI
    }
}

// ---------------------------------------------------------------------------
// One APPNP step (pull), bf16, pair-edge gathers. Wave per node. Half-wave per
// edge: lane (hi=lane>>5, l32=lane&31) loads uint2 = channels 4*l32..4*l32+3 of
// edge (j + hi) -> one instruction fetches two full 512 B rows; 4 instrs per 8
// edges, 16 edges in flight. Halves combined with one shfl_xor(32).
__global__ __launch_bounds__(256) void prop_k(
        const unsigned* __restrict__ zin, const unsigned* __restrict__ x0,
        const int* __restrict__ row_off, const int2* __restrict__ ep,
        unsigned* __restrict__ zout, int fuse_ln,
        const float* __restrict__ gamma, const float* __restrict__ beta) {
    int gw = (blockIdx.x * 256 + threadIdx.x) >> 6;   // node id
    if (gw >= N_NODES) return;
    int lane = threadIdx.x & 63;
    int hi   = lane >> 5;                              // which edge of the pair
    int l32  = lane & 31;
    int s0 = row_off[gw];
    int s1 = row_off[gw + 1];                          // padded degree (x8)
    const uint2* zp = (const uint2*)zin;
    float c0 = 0.f, c1 = 0.f, c2 = 0.f, c3 = 0.f;      // ch 4*l32..+3, my half
    for (int base = s0; base < s1; base += 64) {
        int cnt = min(64, s1 - base);                  // multiple of 8
        int2 p = make_int2(0, 0);
        if (lane < cnt) p = ep[base + lane];
        for (int j = 0; j < cnt; j += 8) {
            int i0 = j + hi;                           // dynamic-index shfl (bpermute)
            int   o0 = __shfl(p.x, i0);     float w0 = __int_as_float(__shfl(p.y, i0));
            int   o1 = __shfl(p.x, i0 + 2); float w1 = __int_as_float(__shfl(p.y, i0 + 2));
            int   o2 = __shfl(p.x, i0 + 4); float w2 = __int_as_float(__shfl(p.y, i0 + 4));
            int   o3 = __shfl(p.x, i0 + 6); float w3 = __int_as_float(__shfl(p.y, i0 + 6));
            uint2 v0 = zp[(o0 >> 1) + l32];
            uint2 v1 = zp[(o1 >> 1) + l32];
            uint2 v2 = zp[(o2 >> 1) + l32];
            uint2 v3 = zp[(o3 >> 1) + l32];
            c0 = fmaf(w0, bf_lo(v0.x), c0); c1 = fmaf(w0, bf_hi(v0.x), c1);
            c2 = fmaf(w0, bf_lo(v0.y), c2); c3 = fmaf(w0, bf_hi(v0.y), c3);
            c0 = fmaf(w1, bf_lo(v1.x), c0); c1 = fmaf(w1, bf_hi(v1.x), c1);
            c2 = fmaf(w1, bf_lo(v1.y), c2); c3 = fmaf(w1, bf_hi(v1.y), c3);
            c0 = fmaf(w2, bf_lo(v2.x), c0); c1 = fmaf(w2, bf_hi(v2.x), c1);
            c2 = fmaf(w2, bf_lo(v2.y), c2); c3 = fmaf(w2, bf_hi(v2.y), c3);
            c0 = fmaf(w3, bf_lo(v3.x), c0); c1 = fmaf(w3, bf_hi(v3.x), c1);
            c2 = fmaf(w3, bf_lo(v3.y), c2); c3 = fmaf(w3, bf_hi(v3.y), c3);
        }
    }
    // combine even-edge (lower half) and odd-edge (upper half) partials
    c0 += __shfl_xor(c0, 32); c1 += __shfl_xor(c1, 32);
    c2 += __shfl_xor(c2, 32); c3 += __shfl_xor(c3, 32);
    uint2 xd = ((const uint2*)x0)[(size_t)gw * 32 + l32];
    float z0 = fmaf(ALPHA, bf_lo(xd.x), c0);
    float z1 = fmaf(ALPHA, bf_hi(xd.x), c1);
    float z2 = fmaf(ALPHA, bf_lo(xd.y), c2);
    float z3 = fmaf(ALPHA, bf_hi(xd.y), c3);
    uint2 od;
    if (fuse_ln) {
        float h0 = gelu_exact(z0), h1 = gelu_exact(z1);
        float h2 = gelu_exact(z2), h3 = gelu_exact(z3);
        float sum = h0 + h1 + h2 + h3;
        for (int off = 16; off; off >>= 1) sum += __shfl_xor(sum, off); // in-half
        float mu = sum * (1.0f / 128.0f);
        float d0 = h0 - mu, d1 = h1 - mu, d2 = h2 - mu, d3 = h3 - mu;
        float vs = d0 * d0 + d1 * d1 + d2 * d2 + d3 * d3;
        for (int off = 16; off; off >>= 1) vs += __shfl_xor(vs, off);
        float inv = rsqrtf(vs * (1.0f / 128.0f) + LN_EPS);
        float4 g4 = ((const float4*)gamma)[l32];
        float4 b4 = ((const float4*)beta)[l32];
        od.x = pack_bf16_rne(g4.x * d0 * inv + b4.x, g4.y * d1 * inv + b4.y);
        od.y = pack_bf16_rne(g4.z * d2 * inv + b4.z, g4.w * d3 * inv + b4.w);
    } else {
        od.x = pack_bf16_rne(z0, z1);
        od.y = pack_bf16_rne(z2, z3);
    }
    if (hi == 0) ((uint2*)zout)[(size_t)gw * 32 + l32] = od;   // 256 B/row store
}

// ---------------------------------------------------------------------------
// Decoder: out(fp32) = H(bf16) @ Wdec^T -> [N, 64].  (R5 structure)
__global__ __launch_bounds__(1024) void decoder_k(
        const unsigned* __restrict__ H, const float* __restrict__ Wdec,
        float* __restrict__ out) {
    __shared__ float WT[HID_C * 65];           // WT[k*65 + o]
    __shared__ unsigned XS[16][256];
    for (int i = threadIdx.x; i < OUT_C * HID_C; i += 1024) {
        int o = i >> 7, k = i & 127;
        WT[k * 65 + o] = Wdec[i];
    }
    __syncthreads();
    int lane = threadIdx.x & 63;
    int wid  = threadIdx.x >> 6;
    int wstride = gridDim.x * 16;
    unsigned* xs = XS[wid];
    for (int grp = blockIdx.x * 16 + wid; grp * 4 < N_NODES; grp += wstride) {
        int r0 = grp * 4;
        const unsigned* hp = H + (size_t)r0 * 64;
        xs[lane]       = hp[lane];
        xs[64 + lane]  = hp[64 + lane];
        xs[128 + lane] = hp[128 + lane];
        xs[192 + lane] = hp[192 + lane];
        __builtin_amdgcn_wave_barrier();
        float a0 = 0, a1 = 0, a2 = 0, a3 = 0;
#pragma unroll 4
        for (int k2 = 0; k2 < 64; ++k2) {
            float w0 = WT[(2 * k2) * 65 + lane];
            float w1 = WT[(2 * k2 + 1) * 65 + lane];
            unsigned u0 = xs[k2];
            unsigned u1 = xs[64 + k2];
            unsigned u2 = xs[128 + k2];
            unsigned u3 = xs[192 + k2];
            a0 = fmaf(bf_lo(u0), w0, a0); a0 = fmaf(bf_hi(u0), w1, a0);
            a1 = fmaf(bf_lo(u1), w0, a1); a1 = fmaf(bf_hi(u1), w1, a1);
            a2 = fmaf(bf_lo(u2), w0, a2); a2 = fmaf(bf_hi(u2), w1, a2);
            a3 = fmaf(bf_lo(u3), w0, a3); a3 = fmaf(bf_hi(u3), w1, a3);
        }
        __builtin_amdgcn_wave_barrier();
        out[(size_t)r0 * OUT_C + lane]       = a0;
        out[(size_t)(r0 + 1) * OUT_C + lane] = a1;
        out[(size_t)(r0 + 2) * OUT_C + lane] = a2;
        out[(size_t)(r0 + 3) * OUT_C + lane] = a3;
    }
}

// ---------------------------------------------------------------------------
extern "C" void kernel_launch(void* const* d_in, const int* in_sizes, int n_in,
                              void* d_out, int out_size, void* d_ws, size_t ws_size,
                              hipStream_t stream) {
    const float* x     = (const float*)d_in[0];
    const int*   ei    = (const int*)d_in[1];
    const float* ew    = (const float*)d_in[2];
    const float* Wenc  = (const float*)d_in[3];
    const float* Wdec  = (const float*)d_in[4];
    const float* gamma = (const float*)d_in[5];
    const float* beta  = (const float*)d_in[6];
    float* out = (float*)d_out;

    const int* src = ei;
    const int* dst = ei + N_EDGES;

    char* p = (char*)d_ws;
    auto carve = [&](size_t bytes) -> void* {
        void* r = (void*)p;
        p += (bytes + 255) & ~(size_t)255;
        return r;
    };
    int*  counts  = (int*)carve(SCAN_N * sizeof(int));
    int*  fillpos = (int*)carve(SCAN_N * sizeof(int));
    int*  row_off = (int*)carve(SCAN_N * sizeof(int));
    int*  bsum    = (int*)carve(SCAN_BLOCKS * sizeof(int));
    int2* ep      = (int2*)carve((size_t)EP_CAP * sizeof(int2));
    unsigned* H  = (unsigned*)carve((size_t)N_NODES * 64 * sizeof(unsigned));
    unsigned* ZA = (unsigned*)carve((size_t)N_NODES * 64 * sizeof(unsigned));
    unsigned* ZB = (unsigned*)carve((size_t)N_NODES * 64 * sizeof(unsigned));

    // CSR build (per launch; deterministic work each call)
    hipMemsetAsync(counts, 0, SCAN_N * sizeof(int), stream);
    hipMemsetAsync(ep, 0, (size_t)EP_CAP * sizeof(int2), stream);  // pads -> (0,0)
    count_k<<<(N_EDGES + 255) / 256, 256, 0, stream>>>(dst, counts);
    scan1_k<<<SCAN_BLOCKS, 1024, 0, stream>>>(counts, bsum);
    scan2_k<<<1, 128, 0, stream>>>(bsum);
    scan3_k<<<SCAN_BLOCKS, 1024, 0, stream>>>(counts, bsum, row_off, fillpos);
    bucket_k<<<(N_EDGES + 255) / 256, 256, 0, stream>>>(src, dst, ew, fillpos, ep);

    // Encoder
    encoder_k<<<512, 1024, 0, stream>>>(x, Wenc, gamma, beta, H);

    const int prop_blocks = (N_NODES + 3) / 4;   // 1 node/wave, 4 waves/block
    unsigned* bufs[2] = {ZA, ZB};
    for (int l = 0; l < NLAYERS; ++l) {
        const unsigned* zin = H;                  // x0 = H (layer input)
        for (int k = 0; k < KSTEPS; ++k) {
            int last = (k == KSTEPS - 1);
            unsigned* zout = last ? H : bufs[k & 1];
            prop_k<<<prop_blocks, 256, 0, stream>>>(zin, H, row_off, ep, zout,
                                                    last, gamma, beta);
            zin = zout;
        }
    }

    decoder_k<<<512, 1024, 0, stream>>>(H, Wdec, out);
}